// Round 16
// baseline (288.839 us; speedup 1.0000x reference)
//
#include <hip/hip_runtime.h>
#include <hip/hip_bf16.h>

typedef __hip_bfloat16 bf16;
#define DEV __device__ __forceinline__

constexpr int B_ = 2, C_ = 64, H_ = 96, W_ = 96, L_ = 9216;
constexpr int HD_ = 32, DI_ = 64, N_ = 16, K_ = 4, BB_ = 4;
constexpr int OC_ = 128;
constexpr int CH_ = 192, CL_ = 48;          // scan chunking: 192 chunks of 48 steps
constexpr int CLH = 24;                     // half-chunk (u-prefetch granularity)
constexpr int SEGN = 32, SEGC = 6;          // scan2: 32 segments x 6 chunks
constexpr int BROW = 20;                    // f32 slots per scan-order B row (16 B + t0,t1 + pad2)
constexpr float EPSF = 1e-5f;
constexpr int DOWN_SZ = B_ * OC_ * 48 * 48; // 589824

typedef __attribute__((ext_vector_type(8))) short short8;   // 8 bf16 (4 VGPRs)
typedef __attribute__((ext_vector_type(4))) float f32x4;    // MFMA accumulator / b128 LDS read
typedef __attribute__((ext_vector_type(2))) float f32x2;    // packed v_pk_* pair

DEV float softplusf(float x) { return x > 15.f ? x : __logf(1.f + __expf(x)); }
DEV float b2f(bf16 v) { return __bfloat162float(v); }
DEV float lo16f(unsigned v) { return __uint_as_float(v << 16); }
DEV float hi16f(unsigned v) { return __uint_as_float(v & 0xffff0000u); }
DEV f32x2 pk2(unsigned w) { f32x2 r = {lo16f(w), hi16f(w)}; return r; }
DEV f32x2 lo2(f32x4 q) { f32x2 r = {q.x, q.y}; return r; }
DEV f32x2 hi2(f32x4 q) { f32x2 r = {q.z, q.w}; return r; }
DEV unsigned pkbf(float a, float b) {
  __hip_bfloat162 t;
  t.x = __float2bfloat16(a);
  t.y = __float2bfloat16(b);
  return *reinterpret_cast<unsigned*>(&t);
}
DEV void unpk8(uint4 a, float* v) {
  v[0] = lo16f(a.x); v[1] = hi16f(a.x); v[2] = lo16f(a.y); v[3] = hi16f(a.y);
  v[4] = lo16f(a.z); v[5] = hi16f(a.z); v[6] = lo16f(a.w); v[7] = hi16f(a.w);
}
DEV void unpk(uint4 a, uint4 b, float* v) {
  unpk8(a, v); unpk8(b, v + 8);
}

// log(1..16): detect A[n] = (n+1)*A[0] structure (VMamba default A_logs)
__constant__ float kLogN[16] = {
  0.0f, 0.69314718f, 1.09861229f, 1.38629436f, 1.60943791f, 1.79175947f,
  1.94591015f, 2.07944154f, 2.19722458f, 2.30258509f, 2.39789527f,
  2.48490665f, 2.56494936f, 2.63905733f, 2.70805020f, 2.77258872f};

// 16 decay powers e1^(n+1) as 8 packed pairs: {e1,e2},{e3,e4},...,{e15,e16}
DEV void pow_tree2(float e1, f32x2* ep) {
  float e2 = e1 * e1;
  ep[0].x = e1; ep[0].y = e2;
  f32x2 b2v = {e2, e2};
  ep[1] = ep[0] * b2v;                       // e3,e4
  float e4 = ep[1].y;
  f32x2 b4v = {e4, e4};
  ep[2] = ep[0] * b4v;                       // e5,e6
  ep[3] = ep[1] * b4v;                       // e7,e8
  float e8 = ep[3].y;
  f32x2 b8v = {e8, e8};
  ep[4] = ep[0] * b8v;                       // e9,e10
  ep[5] = ep[1] * b8v;                       // e11,e12
  ep[6] = ep[2] * b8v;                       // e13,e14
  ep[7] = ep[3] * b8v;                       // e15,e16
}

// ---------------- 1: FRONT — wprep + depthwise3x3 + LN(32) + in_proj (32-idx tiles) ----------------
__global__ __launch_bounds__(256, 4) void k_front(
    const float* __restrict__ x, const float* __restrict__ dw33w,
    const float* __restrict__ dw33b, const float* __restrict__ lnw,
    const float* __restrict__ lnb, const float* __restrict__ inw,
    const float* __restrict__ xpw, const float* __restrict__ alog,
    float* __restrict__ xd, bf16* __restrict__ xzAh, bf16* __restrict__ xzBh,
    bf16* __restrict__ wh, float* __restrict__ aux) {
  int bb = blockIdx.y, t = threadIdx.x;
  int b = bb & 1, co = (bb >> 1) * HD_;
  int idx0 = blockIdx.x * 32;
  if (bb == 0) {
    int i = blockIdx.x * 256 + t;
    if (i < 144 * 64) {
      int n = i >> 6;
      wh[i] = __float2bfloat16(n < 136 ? xpw[i] : 0.f);
    }
    if (blockIdx.x == 0) {
      int kd = t;  // 256 = K*DI
      const float* al = alog + kd * N_;
      float a0 = al[0];
      bool lin = true;
#pragma unroll
      for (int n = 1; n < N_; n++) lin = lin && (fabsf(al[n] - a0 - kLogN[n]) < 3e-5f);
      aux[kd] = -__expf(a0);
      aux[256 + kd] = lin ? 1.f : 0.f;
#pragma unroll
      for (int n = 0; n < N_; n++) aux[512 + kd * N_ + n] = -__expf(al[n]);
    }
  }
  __shared__ float xds[32 * 36];
  __shared__ float meanA[32], rstdA[32];
  for (int i = t; i < 1024; i += 256) {
    int cl = i >> 5, ii = i & 31;
    int sp = idx0 + ii, wi = sp % 96, hi = sp / 96;
    int cg = b * C_ + co + cl;
    float acc = dw33b[co + cl];
#pragma unroll
    for (int dy = -1; dy <= 1; dy++) {
      int hh = hi + dy; if (hh < 0 || hh >= H_) continue;
#pragma unroll
      for (int dx = -1; dx <= 1; dx++) {
        int ww = wi + dx; if (ww < 0 || ww >= W_) continue;
        acc = fmaf(x[(size_t)cg * L_ + sp + dy * 96 + dx],
                   dw33w[(co + cl) * 9 + (dy + 1) * 3 + (dx + 1)], acc);
      }
    }
    xds[cl * 36 + ii] = acc;
    xd[(size_t)cg * L_ + sp] = acc;
  }
  __syncthreads();
  if (t < 32) {
    float s = 0.f, sq = 0.f;
#pragma unroll
    for (int c = 0; c < 32; c++) { float v = xds[c * 36 + t]; s += v; sq = fmaf(v, v, sq); }
    float mean = s * (1.f / HD_);
    float var = sq * (1.f / HD_) - mean * mean;
    meanA[t] = mean; rstdA[t] = rsqrtf(var + EPSF);
  }
  __syncthreads();
  for (int i = t; i < 1024; i += 256) {
    int c = i >> 5, idx = i & 31;
    float v = xds[c * 36 + idx];
    xds[c * 36 + idx] = (v - meanA[idx]) * rstdA[idx] * lnw[c] + lnb[c];
  }
  __syncthreads();
  int oc = t & 127, g = t >> 7;
  float acc[16];
#pragma unroll
  for (int j = 0; j < 16; j++) acc[j] = 0.f;
  for (int c = 0; c < 32; c++) {
    float wv = inw[c * 128 + oc];
    const float4* row = reinterpret_cast<const float4*>(&xds[c * 36 + g * 16]);
#pragma unroll
    for (int j4 = 0; j4 < 4; j4++) {
      float4 xv = row[j4];
      acc[j4 * 4 + 0] = fmaf(xv.x, wv, acc[j4 * 4 + 0]);
      acc[j4 * 4 + 1] = fmaf(xv.y, wv, acc[j4 * 4 + 1]);
      acc[j4 * 4 + 2] = fmaf(xv.z, wv, acc[j4 * 4 + 2]);
      acc[j4 * 4 + 3] = fmaf(xv.w, wv, acc[j4 * 4 + 3]);
    }
  }
  int occ = oc & 63;
  if (oc < 64) {
#pragma unroll
    for (int j = 0; j < 16; j++)
      xzAh[(size_t)(bb * L_ + idx0 + g * 16 + j) * 64 + occ] = __float2bfloat16(acc[j]);
  } else {
#pragma unroll
    for (int j = 0; j < 16; j++)
      xzBh[(size_t)(bb * L_ + idx0 + g * 16 + j) * 64 + occ] = __float2bfloat16(acc[j]);
  }
}

// ---------------- 2: depthwise 3x3 + SiLU — 2 rows x 2 channels per thread ----------------
__global__ void k_dwsilu(const bf16* __restrict__ xzAh, const float* __restrict__ cw,
                         const float* __restrict__ cb, bf16* __restrict__ xch,
                         bf16* __restrict__ xcht) {
  int t = blockIdx.x * 256 + threadIdx.x;       // over (L/2)*32 pair-items
  int dp = t & 31, rp = t >> 5;                 // rp in [0, 4608)
  int bb = blockIdx.y;
  int d0 = dp * 2;
  int wi = rp % 96, hp = rp / 96;
  int hi0 = hp * 2;                             // rows hi0, hi0+1
  const unsigned* src = (const unsigned*)xzAh;  // bf16 pairs
  float a00 = cb[d0], a01 = cb[d0 + 1];
  float a10 = a00, a11 = a01;
#pragma unroll
  for (int r4 = 0; r4 < 4; r4++) {
    int rr = hi0 - 1 + r4;
    if (rr < 0 || rr >= H_) continue;
#pragma unroll
    for (int c3 = 0; c3 < 3; c3++) {
      int cc = wi - 1 + c3;
      if (cc < 0 || cc >= W_) continue;
      unsigned v = src[(size_t)(bb * L_ + rr * 96 + cc) * 32 + dp];
      float vl = lo16f(v), vh = hi16f(v);
      if (r4 <= 2) {                            // row0: dy = r4-1 -> weight row r4
        a00 = fmaf(vl, cw[d0 * 9 + r4 * 3 + c3], a00);
        a01 = fmaf(vh, cw[(d0 + 1) * 9 + r4 * 3 + c3], a01);
      }
      if (r4 >= 1) {                            // row1: dy = r4-2 -> weight row r4-1
        a10 = fmaf(vl, cw[d0 * 9 + (r4 - 1) * 3 + c3], a10);
        a11 = fmaf(vh, cw[(d0 + 1) * 9 + (r4 - 1) * 3 + c3], a11);
      }
    }
  }
  a00 = a00 / (1.f + __expf(-a00));
  a01 = a01 / (1.f + __expf(-a01));
  a10 = a10 / (1.f + __expf(-a10));
  a11 = a11 / (1.f + __expf(-a11));
  unsigned o0 = pkbf(a00, a01), o1 = pkbf(a10, a11);
  int idx0 = hi0 * 96 + wi;
  ((unsigned*)xch)[((size_t)bb * L_ + idx0) * 32 + dp] = o0;
  ((unsigned*)xch)[((size_t)bb * L_ + idx0 + 96) * 32 + dp] = o1;
  int it0 = wi * 96 + hi0;
  ((unsigned*)xcht)[((size_t)bb * L_ + it0) * 32 + dp] = o0;
  ((unsigned*)xcht)[((size_t)bb * L_ + it0 + 1) * 32 + dp] = o1;
}

// ---------------- 3: x_dbl proj via MFMA -> scan-order xdblB / xdblC (f32, nt split on z) ----------------
__global__ __launch_bounds__(256, 4) void k_xdbl_mfma(
    const bf16* __restrict__ xch, const bf16* __restrict__ wh,
    float* __restrict__ xdblB, float* __restrict__ xdblC) {
  int w = threadIdx.x >> 6, lane = threadIdx.x & 63;
  int bb = blockIdx.y;
  int mtile = blockIdx.x * 4 + w;
  int idx0 = mtile * 16;
  int m = lane & 15, quad = lane >> 4;
  const bf16* arow = xch + ((size_t)bb * L_ + idx0 + m) * 64 + quad * 8;
  short8 a0 = *reinterpret_cast<const short8*>(arow);
  short8 a1 = *reinterpret_cast<const short8*>(arow + 32);
  int ntb = blockIdx.z * 3;
#pragma unroll
  for (int it = 0; it < 3; it++) {
    int nt = ntb + it;
    int n = nt * 16 + m;
    const bf16* brow = wh + n * 64 + quad * 8;
    short8 b0 = *reinterpret_cast<const short8*>(brow);
    short8 b1 = *reinterpret_cast<const short8*>(brow + 32);
    f32x4 acc = {0.f, 0.f, 0.f, 0.f};
    acc = __builtin_amdgcn_mfma_f32_16x16x32_bf16(a0, b0, acc, 0, 0, 0);
    acc = __builtin_amdgcn_mfma_f32_16x16x32_bf16(a1, b1, acc, 0, 0, 0);
    if (n < 136) {
      int k4 = (n >= 102) ? 3 : (n >= 68) ? 2 : (n >= 34) ? 1 : 0;
      int c = n - k4 * 34;
#pragma unroll
      for (int i = 0; i < 4; i++) {
        int r = idx0 + quad * 4 + i;
        int hi2 = r / 96, wi2 = r - hi2 * 96;
        int tr = wi2 * 96 + hi2;
        int ls = (k4 == 0) ? r : (k4 == 1) ? tr : (k4 == 2) ? (L_ - 1 - r) : (L_ - 1 - tr);
        size_t row = (size_t)(bb * K_ + k4) * L_ + ls;
        if (c < 2)       xdblB[row * BROW + 16 + c] = acc[i];
        else if (c < 18) xdblB[row * BROW + (c - 2)] = acc[i];
        else             xdblC[row * 16 + (c - 18)] = acc[i];
      }
    }
  }
}

// ---------------- 4: scan1 — per-chunk summaries (48 steps, 2 u-prefetch halves) ----------------
__global__ __launch_bounds__(256, 4) void k_scan1(
    const float* __restrict__ xdblB, const bf16* __restrict__ xch,
    const bf16* __restrict__ xcht, const float* __restrict__ dtw,
    const float* __restrict__ dtb, const float* __restrict__ aux,
    bf16* __restrict__ hbuf, float* __restrict__ ssum) {
  int w = threadIdx.x >> 6, d = threadIdx.x & 63;
  int bx = blockIdx.x;
  int chunk = bx * 4 + w, k = blockIdx.y, bb = blockIdx.z;
  const float* bB = xdblB + (size_t)(bb * K_ + k) * L_ * BROW;
  __shared__ __align__(16) float sB[192 * BROW];   // 15360 B
  {
    const uint4* src = (const uint4*)(bB + (size_t)bx * 192 * BROW);
    uint4* dst = (uint4*)sB;
    for (int i = threadIdx.x; i < 960; i += 256) dst[i] = src[i];
  }
  __syncthreads();
  float w0 = dtw[(k * DI_ + d) * 2 + 0], w1 = dtw[(k * DI_ + d) * 2 + 1];
  float bia = dtb[k * DI_ + d];
  float A1 = aux[k * 64 + d];
  bool chain = (__ballot(aux[256 + k * 64 + d] > 0.5f) == ~0ull);
  const bf16* ub = ((k & 1) ? xcht : xch) + (size_t)bb * L_ * DI_;
  int ls0 = chunk * CL_;
  int uidx0 = (k & 2) ? (L_ - 1 - ls0) : ls0;
  int ustep = (k & 2) ? -1 : 1;
  float S = 0.f;
  size_t base = (size_t)((bb * K_ + k) * CH_ + chunk) * DI_ + d;
  if (chain) {
    f32x2 h2[8];
#pragma unroll
    for (int i = 0; i < 8; i++) { h2[i].x = 0.f; h2[i].y = 0.f; }
    for (int half = 0; half < 2; half++) {
      float uv[CLH];
      const bf16* up = ub + (size_t)(uidx0 + half * CLH * ustep) * DI_ + d;
#pragma unroll
      for (int s = 0; s < CLH; s++) uv[s] = b2f(up[s * ustep * DI_]);
#pragma unroll
      for (int s = 0; s < CLH; s++) {
        const float* p = sB + (w * CL_ + half * CLH + s) * BROW;
        f32x4 q0 = *(const f32x4*)p;
        f32x4 q1 = *(const f32x4*)(p + 4);
        f32x4 q2 = *(const f32x4*)(p + 8);
        f32x4 q3 = *(const f32x4*)(p + 12);
        f32x2 tt = *(const f32x2*)(p + 16);
        float dt = softplusf(fmaf(tt.x, w0, fmaf(tt.y, w1, bia)));
        S += dt;
        float du = dt * uv[s];
        f32x2 du2 = {du, du};
        f32x2 ep2[8];
        pow_tree2(__expf(dt * A1), ep2);
        h2[0] = ep2[0] * h2[0] + du2 * lo2(q0);
        h2[1] = ep2[1] * h2[1] + du2 * hi2(q0);
        h2[2] = ep2[2] * h2[2] + du2 * lo2(q1);
        h2[3] = ep2[3] * h2[3] + du2 * hi2(q1);
        h2[4] = ep2[4] * h2[4] + du2 * lo2(q2);
        h2[5] = ep2[5] * h2[5] + du2 * hi2(q2);
        h2[6] = ep2[6] * h2[6] + du2 * lo2(q3);
        h2[7] = ep2[7] * h2[7] + du2 * hi2(q3);
      }
    }
    uint4 o0, o1;
    o0.x = pkbf(h2[0].x, h2[0].y); o0.y = pkbf(h2[1].x, h2[1].y);
    o0.z = pkbf(h2[2].x, h2[2].y); o0.w = pkbf(h2[3].x, h2[3].y);
    o1.x = pkbf(h2[4].x, h2[4].y); o1.y = pkbf(h2[5].x, h2[5].y);
    o1.z = pkbf(h2[6].x, h2[6].y); o1.w = pkbf(h2[7].x, h2[7].y);
    *(uint4*)(hbuf + base * N_) = o0;
    *(uint4*)(hbuf + base * N_ + 8) = o1;
  } else {
    float h[N_];
#pragma unroll
    for (int n = 0; n < N_; n++) h[n] = 0.f;
    float A[N_];
#pragma unroll
    for (int n = 0; n < N_; n++) A[n] = aux[512 + (k * 64 + d) * N_ + n];
    for (int s = 0; s < CL_; s++) {
      const float* p = sB + (w * CL_ + s) * BROW;
      float u = b2f(ub[(size_t)(uidx0 + s * ustep) * DI_ + d]);
      float dt = softplusf(fmaf(p[16], w0, fmaf(p[17], w1, bia)));
      S += dt;
      float du = dt * u;
#pragma unroll
      for (int n = 0; n < N_; n++) h[n] = fmaf(__expf(dt * A[n]), h[n], du * p[n]);
    }
#pragma unroll
    for (int n = 0; n < N_; n++) hbuf[base * N_ + n] = __float2bfloat16(h[n]);
  }
  ssum[base] = S;
}

// ---------------- 5: scan2a — segment-local exclusive scan + raw segment totals ----------------
__global__ __launch_bounds__(256, 4) void k_scan2a(
    const float* __restrict__ aux, const float* __restrict__ ssum,
    bf16* __restrict__ hbuf, float* __restrict__ cumS,
    float* __restrict__ segH, float* __restrict__ segS) {
  int t = blockIdx.x * 256 + threadIdx.x;      // 524288
  int n = t & 15, d = (t >> 4) & 63, kk = (t >> 10) & 3, bb = (t >> 12) & 3, seg = t >> 14;
  float A = aux[512 + (kk * 64 + d) * N_ + n];
  size_t row = (size_t)(bb * K_ + kk) * CH_ * DI_ + d;
  float hp = 0.f, Sc = 0.f;
#pragma unroll
  for (int j = 0; j < SEGC; j++) {
    int c = seg * SEGC + j;
    size_t sb = row + (size_t)c * DI_;
    float S = ssum[sb];
    float hl = b2f(hbuf[sb * N_ + n]);
    hbuf[sb * N_ + n] = __float2bfloat16(hp);
    if (n == 0) cumS[sb] = Sc;
    hp = fmaf(__expf(A * S), hp, hl);
    Sc += S;
  }
  size_t sbase = (size_t)(bb * K_ + kk) * SEGN + seg;
  segH[(sbase * DI_ + d) * N_ + n] = hp;
  if (n == 0) segS[sbase * DI_ + d] = Sc;
}

// ---------------- 6: scan2b — serial scan over 32 segments (tiny) ----------------
__global__ void k_scan2b(const float* __restrict__ aux, float* __restrict__ segH,
                         const float* __restrict__ segS) {
  int t = blockIdx.x * 256 + threadIdx.x;  // 16384
  int n = t & 15, d = (t >> 4) & 63, kk = (t >> 10) & 3, bb = t >> 12;
  float A = aux[512 + (kk * 64 + d) * N_ + n];
  float hp = 0.f;
  for (int seg = 0; seg < SEGN; seg++) {
    size_t sbase = (size_t)(bb * K_ + kk) * SEGN + seg;
    size_t si = (sbase * DI_ + d) * N_ + n;
    float H = segH[si];
    float E = __expf(A * segS[sbase * DI_ + d]);
    segH[si] = hp;                          // overwrite with segment-initial state
    hp = fmaf(E, hp, H);
  }
}

// ---------------- 7: scan3 — replay (48 steps, 2 halves); headers hoisted above staging ----------------
__global__ __launch_bounds__(256, 4) void k_scan3(
    const float* __restrict__ xdblB, const float* __restrict__ xdblC,
    const bf16* __restrict__ xch, const bf16* __restrict__ xcht,
    const float* __restrict__ dtw, const float* __restrict__ dtb,
    const float* __restrict__ Dsw, const float* __restrict__ aux,
    const bf16* __restrict__ hbuf, const float* __restrict__ cumS,
    const float* __restrict__ segH, bf16* __restrict__ ydir) {
  int w = threadIdx.x >> 6, d = threadIdx.x & 63;
  int bx = blockIdx.x;
  int chunk = bx * 4 + w, k = blockIdx.y, bb = blockIdx.z;
  // --- early header loads: issue before LDS staging so latency overlaps it ---
  size_t base = (size_t)((bb * K_ + k) * CH_ + chunk) * DI_ + d;
  int seg = chunk / SEGC;
  size_t sbase = (size_t)(bb * K_ + k) * SEGN + seg;
  float Sc = cumS[base];
  const bf16* hb = hbuf + base * N_;
  uint4 qh0 = *(const uint4*)hb, qh1 = *(const uint4*)(hb + 8);
  const float* Hinp = segH + (sbase * DI_ + d) * N_;
  f32x4 hin0 = *(const f32x4*)Hinp;
  f32x4 hin1 = *(const f32x4*)(Hinp + 4);
  f32x4 hin2 = *(const f32x4*)(Hinp + 8);
  f32x4 hin3 = *(const f32x4*)(Hinp + 12);
  float w0 = dtw[(k * DI_ + d) * 2 + 0], w1 = dtw[(k * DI_ + d) * 2 + 1];
  float bia = dtb[k * DI_ + d];
  float Dk = Dsw[k * DI_ + d];
  float A1 = aux[k * 64 + d];
  bool chain = (__ballot(aux[256 + k * 64 + d] > 0.5f) == ~0ull);
  // --- LDS staging ---
  const float* bB = xdblB + (size_t)(bb * K_ + k) * L_ * BROW;
  const float* bC = xdblC + (size_t)(bb * K_ + k) * L_ * 16;
  __shared__ __align__(16) float sB[192 * BROW];   // 15360 B
  __shared__ __align__(16) float sC[192 * 16];     // 12288 B
  {
    const uint4* srcB = (const uint4*)(bB + (size_t)bx * 192 * BROW);
    uint4* dstB = (uint4*)sB;
    for (int i = threadIdx.x; i < 960; i += 256) dstB[i] = srcB[i];
    const uint4* srcC = (const uint4*)(bC + (size_t)bx * 192 * 16);
    uint4* dstC = (uint4*)sC;
    for (int i = threadIdx.x; i < 768; i += 256) dstC[i] = srcC[i];
  }
  __syncthreads();
  const bf16* ub = ((k & 1) ? xcht : xch) + (size_t)bb * L_ * DI_;
  bf16* yb = ydir + (size_t)(bb * K_ + k) * L_ * DI_;
  int ls0 = chunk * CL_;
  int uidx0 = (k & 2) ? (L_ - 1 - ls0) : ls0;
  int ustep = (k & 2) ? -1 : 1;
  if (chain) {
    f32x2 h2[8];
    {
      h2[0] = pk2(qh0.x); h2[1] = pk2(qh0.y); h2[2] = pk2(qh0.z); h2[3] = pk2(qh0.w);
      h2[4] = pk2(qh1.x); h2[5] = pk2(qh1.y); h2[6] = pk2(qh1.z); h2[7] = pk2(qh1.w);
      f32x2 ep2[8];
      pow_tree2(__expf(A1 * Sc), ep2);
      h2[0] = ep2[0] * lo2(hin0) + h2[0];
      h2[1] = ep2[1] * hi2(hin0) + h2[1];
      h2[2] = ep2[2] * lo2(hin1) + h2[2];
      h2[3] = ep2[3] * hi2(hin1) + h2[3];
      h2[4] = ep2[4] * lo2(hin2) + h2[4];
      h2[5] = ep2[5] * hi2(hin2) + h2[5];
      h2[6] = ep2[6] * lo2(hin3) + h2[6];
      h2[7] = ep2[7] * hi2(hin3) + h2[7];
    }
    for (int half = 0; half < 2; half++) {
      float uv[CLH];
      const bf16* up = ub + (size_t)(uidx0 + half * CLH * ustep) * DI_ + d;
#pragma unroll
      for (int s = 0; s < CLH; s++) uv[s] = b2f(up[s * ustep * DI_]);
#pragma unroll
      for (int s = 0; s < CLH; s++) {
        int lr = w * CL_ + half * CLH + s;
        const float* p = sB + lr * BROW;
        const float* pc = sC + lr * 16;
        f32x4 q0 = *(const f32x4*)p;
        f32x4 q1 = *(const f32x4*)(p + 4);
        f32x4 q2 = *(const f32x4*)(p + 8);
        f32x4 q3 = *(const f32x4*)(p + 12);
        f32x2 tt = *(const f32x2*)(p + 16);
        f32x4 c0 = *(const f32x4*)pc;
        f32x4 c1 = *(const f32x4*)(pc + 4);
        f32x4 c2 = *(const f32x4*)(pc + 8);
        f32x4 c3 = *(const f32x4*)(pc + 12);
        float dt = softplusf(fmaf(tt.x, w0, fmaf(tt.y, w1, bia)));
        float du = dt * uv[s];
        f32x2 du2 = {du, du};
        f32x2 ep2[8];
        pow_tree2(__expf(dt * A1), ep2);
        f32x2 y2 = {0.f, 0.f};
        h2[0] = ep2[0] * h2[0] + du2 * lo2(q0);  y2 = h2[0] * lo2(c0) + y2;
        h2[1] = ep2[1] * h2[1] + du2 * hi2(q0);  y2 = h2[1] * hi2(c0) + y2;
        h2[2] = ep2[2] * h2[2] + du2 * lo2(q1);  y2 = h2[2] * lo2(c1) + y2;
        h2[3] = ep2[3] * h2[3] + du2 * hi2(q1);  y2 = h2[3] * hi2(c1) + y2;
        h2[4] = ep2[4] * h2[4] + du2 * lo2(q2);  y2 = h2[4] * lo2(c2) + y2;
        h2[5] = ep2[5] * h2[5] + du2 * hi2(q2);  y2 = h2[5] * hi2(c2) + y2;
        h2[6] = ep2[6] * h2[6] + du2 * lo2(q3);  y2 = h2[6] * lo2(c3) + y2;
        h2[7] = ep2[7] * h2[7] + du2 * hi2(q3);  y2 = h2[7] * hi2(c3) + y2;
        float y = fmaf(Dk, uv[s], y2.x + y2.y);
        yb[(size_t)(ls0 + half * CLH + s) * DI_ + d] = __float2bfloat16(y);
      }
    }
  } else {
    float h[N_];
    float hin[N_];
    {
      *(f32x4*)(hin + 0) = hin0; *(f32x4*)(hin + 4) = hin1;
      *(f32x4*)(hin + 8) = hin2; *(f32x4*)(hin + 12) = hin3;
      unpk(qh0, qh1, h);
#pragma unroll
      for (int n = 0; n < N_; n++) {
        float A = aux[512 + (k * 64 + d) * N_ + n];
        h[n] = fmaf(__expf(A * Sc), hin[n], h[n]);
      }
    }
    float A[N_];
#pragma unroll
    for (int n = 0; n < N_; n++) A[n] = aux[512 + (k * 64 + d) * N_ + n];
    for (int s = 0; s < CL_; s++) {
      int lr = w * CL_ + s;
      const float* p = sB + lr * BROW;
      const float* pc = sC + lr * 16;
      float u = b2f(ub[(size_t)(uidx0 + s * ustep) * DI_ + d]);
      float dt = softplusf(fmaf(p[16], w0, fmaf(p[17], w1, bia)));
      float du = dt * u;
      float y = 0.f;
#pragma unroll
      for (int n = 0; n < N_; n++) {
        h[n] = fmaf(__expf(dt * A[n]), h[n], du * p[n]);
        y = fmaf(h[n], pc[n], y);
      }
      y = fmaf(Dk, u, y);
      yb[(size_t)(ls0 + s) * DI_ + d] = __float2bfloat16(y);
    }
  }
}

// ---------------- 8: combine — 2 idx/warp ILP; 4 dirs, LN(64)*silu(z), out_proj, residual ----------------
__global__ void k_combine(const bf16* __restrict__ ydir, const bf16* __restrict__ xzBh,
                          const float* __restrict__ xd, const float* __restrict__ onw,
                          const float* __restrict__ onb, const float* __restrict__ outw,
                          const float* __restrict__ mssc, float* __restrict__ xm) {
  int w = threadIdx.x >> 6, d = threadIdx.x & 63;
  int idxA = blockIdx.x * 8 + w * 2, bb = blockIdx.y;
  int idxB = idxA + 1;
  int b = bb & 1, co = (bb >> 1) * HD_;
  const bf16* yd = ydir + (size_t)bb * K_ * L_ * DI_;
  int hiA = idxA / 96, wiA = idxA - hiA * 96, ltA = wiA * 96 + hiA;
  int hiB = idxB / 96, wiB = idxB - hiB * 96, ltB = wiB * 96 + hiB;
  float yA = b2f(yd[((size_t)0 * L_ + idxA) * DI_ + d])
           + b2f(yd[((size_t)1 * L_ + ltA) * DI_ + d])
           + b2f(yd[((size_t)2 * L_ + (L_ - 1 - idxA)) * DI_ + d])
           + b2f(yd[((size_t)3 * L_ + (L_ - 1 - ltA)) * DI_ + d]);
  float yB = b2f(yd[((size_t)0 * L_ + idxB) * DI_ + d])
           + b2f(yd[((size_t)1 * L_ + ltB) * DI_ + d])
           + b2f(yd[((size_t)2 * L_ + (L_ - 1 - idxB)) * DI_ + d])
           + b2f(yd[((size_t)3 * L_ + (L_ - 1 - ltB)) * DI_ + d]);
  float sA = yA, qA = yA * yA, sB = yB, qB = yB * yB;
#pragma unroll
  for (int m = 1; m < 64; m <<= 1) {
    sA += __shfl_xor(sA, m, 64); qA += __shfl_xor(qA, m, 64);
    sB += __shfl_xor(sB, m, 64); qB += __shfl_xor(qB, m, 64);
  }
  float meanA = sA * (1.f / DI_);
  float rstdA = rsqrtf(qA * (1.f / DI_) - meanA * meanA + EPSF);
  float meanB = sB * (1.f / DI_);
  float rstdB = rsqrtf(qB * (1.f / DI_) - meanB * meanB + EPSF);
  float onwd = onw[d], onbd = onb[d];
  float ynA = (yA - meanA) * rstdA * onwd + onbd;
  float ynB = (yB - meanB) * rstdB * onwd + onbd;
  float zA = b2f(xzBh[(size_t)(bb * L_ + idxA) * 64 + d]);
  float zB = b2f(xzBh[(size_t)(bb * L_ + idxB) * 64 + d]);
  float gA = ynA * (zA / (1.f + __expf(-zA)));
  float gB = ynB * (zB / (1.f + __expf(-zB)));
  __shared__ __align__(16) float gs[8][DI_];
  gs[w * 2][d] = gA;
  gs[w * 2 + 1][d] = gB;
  __syncthreads();
  // split-dd out_proj: lanes d<32 sum dd=0..31, lanes d>=32 sum dd=32..63; shfl combines.
  int dh = d & 31;
  int ddb = (d >= 32) ? 32 : 0;
  const float* ga = &gs[w * 2][ddb];
  const float* gb = &gs[w * 2 + 1][ddb];
  float accA = 0.f, accB = 0.f;
#pragma unroll
  for (int j = 0; j < 8; j++) {
    float4 va = *(const float4*)(ga + j * 4);
    float4 vb = *(const float4*)(gb + j * 4);
    int dd = ddb + j * 4;
    float w0 = outw[(dd + 0) * HD_ + dh];
    float w1 = outw[(dd + 1) * HD_ + dh];
    float w2 = outw[(dd + 2) * HD_ + dh];
    float w3 = outw[(dd + 3) * HD_ + dh];
    accA = fmaf(va.x, w0, accA); accB = fmaf(vb.x, w0, accB);
    accA = fmaf(va.y, w1, accA); accB = fmaf(vb.y, w1, accB);
    accA = fmaf(va.z, w2, accA); accB = fmaf(vb.z, w2, accB);
    accA = fmaf(va.w, w3, accA); accB = fmaf(vb.w, w3, accB);
  }
  accA += __shfl_xor(accA, 32, 64);
  accB += __shfl_xor(accB, 32, 64);
  if (d < HD_) {
    float sc = mssc[0] + 1.f;
    size_t xiA = (size_t)(b * C_ + co + d) * L_ + idxA;
    size_t xiB = (size_t)(b * C_ + co + d) * L_ + idxB;
    xm[xiA] = sc * xd[xiA] + accA;
    xm[xiB] = sc * xd[xiB] + accB;
  }
}

// ---------------- 9: fused instance-norm stats (xm) + global mean/max pool (x), float4 ----------------
__global__ __launch_bounds__(1024) void k_stats(
    const float* __restrict__ xm, const float* __restrict__ x,
    float* __restrict__ inm, float* __restrict__ inr,
    float* __restrict__ xmean, float* __restrict__ xmax) {
  int bc = blockIdx.x, t = threadIdx.x;
  const float4* pm4 = (const float4*)(xm + (size_t)bc * L_);
  const float4* px4 = (const float4*)(x + (size_t)bc * L_);
  float s = 0.f, sq = 0.f, xs = 0.f, mx = -1e30f;
  for (int i = t; i < L_ / 4; i += 1024) {
    float4 v = pm4[i];
    s += (v.x + v.y) + (v.z + v.w);
    sq = fmaf(v.x, v.x, sq); sq = fmaf(v.y, v.y, sq);
    sq = fmaf(v.z, v.z, sq); sq = fmaf(v.w, v.w, sq);
    float4 xv = px4[i];
    xs += (xv.x + xv.y) + (xv.z + xv.w);
    mx = fmaxf(mx, fmaxf(fmaxf(xv.x, xv.y), fmaxf(xv.z, xv.w)));
  }
  __shared__ float red[64];
#pragma unroll
  for (int m = 1; m < 64; m <<= 1) {
    s += __shfl_xor(s, m, 64); sq += __shfl_xor(sq, m, 64);
    xs += __shfl_xor(xs, m, 64); mx = fmaxf(mx, __shfl_xor(mx, m, 64));
  }
  int wid = t >> 6;
  if ((t & 63) == 0) { red[wid] = s; red[16 + wid] = sq; red[32 + wid] = xs; red[48 + wid] = mx; }
  __syncthreads();
  if (t == 0) {
    s = 0.f; sq = 0.f; xs = 0.f; mx = -1e30f;
#pragma unroll
    for (int i = 0; i < 16; i++) {
      s += red[i]; sq += red[16 + i]; xs += red[32 + i]; mx = fmaxf(mx, red[48 + i]);
    }
    float mean = s * (1.f / L_);
    float var = sq * (1.f / L_) - mean * mean;
    inm[bc] = mean;
    inr[bc] = rsqrtf(var + EPSF);
    xmean[bc] = xs * (1.f / L_);
    xmax[bc] = mx;
  }
}

// ---------------- 10: axbn — 512 elems/block, 2/thread; IN+leaky+gate + axial convs + BN + relu ----------------
__global__ void k_axbn(const float* __restrict__ xm, const float* __restrict__ x,
                       const float* __restrict__ inm, const float* __restrict__ inr,
                       const float* __restrict__ msw, const float* __restrict__ msb,
                       const float* __restrict__ xmean, const float* __restrict__ xmax,
                       const float* __restrict__ maw, const float* __restrict__ mab,
                       const float* __restrict__ hw, const float* __restrict__ hb,
                       const float* __restrict__ wwt, const float* __restrict__ wb,
                       const float* __restrict__ bnw, const float* __restrict__ bnb,
                       const float* __restrict__ bnm, const float* __restrict__ bnv,
                       float* __restrict__ skipo) {
  constexpr int NEL = B_ * C_ * L_;
  int t0 = blockIdx.x * 512;
  int bc = t0 / L_, c = bc & 63, b = bc >> 6;   // uniform per block (512 | L)
  __shared__ float gsh;
  __shared__ float sxs[704];                    // [t0-96, t0+608) post-IN/leaky/gate values
  if (threadIdx.x < 64) {
    int ic = threadIdx.x;
    float p = xmean[b * 64 + ic] * maw[(c * 128 + ic) * 9 + 4]
            + xmax[b * 64 + ic] * maw[(c * 128 + 64 + ic) * 9 + 4];
#pragma unroll
    for (int m = 1; m < 64; m <<= 1) p += __shfl_xor(p, m, 64);
    if (ic == 0) gsh = 1.f / (1.f + __expf(-(p + mab[c])));
  }
  __syncthreads();
  float gate = gsh, im = inm[bc], ir = inr[bc], mw = msw[c], mb = msb[c];
  // stage: halo values outside valid row range are never consumed (guards below)
  for (int i = threadIdx.x; i < 704; i += 256) {
    int tt = t0 - 96 + i;
    tt = tt < 0 ? 0 : (tt >= NEL ? NEL - 1 : tt);
    float v = xm[tt];
    v = (v - im) * ir * mw + mb;
    v = v > 0.f ? v : 0.01f * v;
    sxs[i] = v + gate * x[tt];
  }
  __syncthreads();
  float hw0 = hw[c * 3], hw1 = hw[c * 3 + 1], hw2 = hw[c * 3 + 2];
  float ww0 = wwt[c * 3], ww1 = wwt[c * 3 + 1], ww2 = wwt[c * 3 + 2];
  float hbc = hb[c], wbc = wb[c];
  float bnr = rsqrtf(bnv[c] + EPSF) * bnw[c];
  float bnmc = bnm[c], bnbc = bnb[c];
#pragma unroll
  for (int e = 0; e < 2; e++) {
    int tid = e * 256 + threadIdx.x;
    int t = t0 + tid;
    int li = 96 + tid;
    int wi = t % W_, hi = (t / W_) % H_;
    float a = sxs[li];
    float hacc = hbc;
    if (hi > 0)      hacc = fmaf(sxs[li - 96], hw0, hacc);
    hacc = fmaf(a, hw1, hacc);
    if (hi < H_ - 1) hacc = fmaf(sxs[li + 96], hw2, hacc);
    float wacc = wbc;
    if (wi > 0)      wacc = fmaf(sxs[li - 1], ww0, wacc);
    wacc = fmaf(a, ww1, wacc);
    if (wi < W_ - 1) wacc = fmaf(sxs[li + 1], ww2, wacc);
    float v = a + hacc + wacc;
    float sv = (v - bnmc) * bnr + bnbc;
    skipo[t] = fmaxf(sv, 0.f);
  }
}

// ---------------- 11: 1x1 conv (64->128) + 2x2 maxpool -> down (oc split over z) ----------------
__global__ void k_pwpool(const float* __restrict__ skipo, const float* __restrict__ pww,
                         const float* __restrict__ pwb, float* __restrict__ down) {
  int h2 = blockIdx.x, b = blockIdx.y, t = threadIdx.x;
  int oc0 = blockIdx.z * 32;
  __shared__ __align__(8) float sk[64 * 192];  // [c][r(2)][w(96)]
  for (int i = t; i < 64 * 192; i += 256) {
    int c = i / 192, rw = i % 192, r = rw / 96, wcol = rw % 96;
    sk[i] = skipo[((size_t)(b * C_ + c) * H_ + (2 * h2 + r)) * W_ + wcol];
  }
  __syncthreads();
  for (int o = t; o < 32 * 48; o += 256) {
    int oc = oc0 + o / 48, w2 = o % 48;
    float s0 = 0.f, s1 = 0.f, s2 = 0.f, s3 = 0.f;
#pragma unroll 8
    for (int c = 0; c < 64; c++) {
      float wv = pww[oc * 64 + c];
      const float2* sp = (const float2*)&sk[c * 192 + 2 * w2];
      float2 r0 = sp[0];        // row 0: w, w+1
      float2 r1 = sp[48];       // row 1: w, w+1 (+96 floats)
      s0 = fmaf(r0.x, wv, s0);
      s1 = fmaf(r0.y, wv, s1);
      s2 = fmaf(r1.x, wv, s2);
      s3 = fmaf(r1.y, wv, s3);
    }
    float v = fmaxf(fmaxf(s0, s1), fmaxf(s2, s3)) + pwb[oc];
    down[((size_t)(b * OC_ + oc) * 48 + h2) * 48 + w2] = v;
  }
}

extern "C" void kernel_launch(void* const* d_in, const int* in_sizes, int n_in,
                              void* d_out, int out_size, void* d_ws, size_t ws_size,
                              hipStream_t stream) {
  const float* x     = (const float*)d_in[0];
  const float* dw33w = (const float*)d_in[1];
  const float* dw33b = (const float*)d_in[2];
  const float* msw   = (const float*)d_in[3];
  const float* msb   = (const float*)d_in[4];
  const float* mssc  = (const float*)d_in[5];
  const float* lnw   = (const float*)d_in[6];
  const float* lnb   = (const float*)d_in[7];
  const float* inw   = (const float*)d_in[8];
  const float* cw    = (const float*)d_in[9];
  const float* cb    = (const float*)d_in[10];
  const float* xpw   = (const float*)d_in[11];
  const float* dtw   = (const float*)d_in[12];
  const float* dtb   = (const float*)d_in[13];
  const float* alog  = (const float*)d_in[14];
  const float* Dsw   = (const float*)d_in[15];
  const float* onw   = (const float*)d_in[16];
  const float* onb   = (const float*)d_in[17];
  const float* outw  = (const float*)d_in[18];
  const float* maw   = (const float*)d_in[19];
  const float* mab   = (const float*)d_in[20];
  const float* ahw   = (const float*)d_in[21];
  const float* ahb   = (const float*)d_in[22];
  const float* aww   = (const float*)d_in[23];
  const float* awb   = (const float*)d_in[24];
  const float* pww   = (const float*)d_in[25];
  const float* pwb   = (const float*)d_in[26];
  const float* bnw   = (const float*)d_in[27];
  const float* bnb   = (const float*)d_in[28];
  const float* bnm   = (const float*)d_in[29];
  const float* bnv   = (const float*)d_in[30];

  // workspace layout (f32 units) — CH=192: hbuf needs 3,145,728 bf16 = 1,572,864 f32;
  // region kept at 3,145,728 f32 (xzAh overlay needs 1,179,648 f32; footprint = R12 layout).
  float* ws = (float*)d_ws;
  float* xd    = ws;                           // 1,179,648
  float* hreg  = xd + 1179648;                 // 3,145,728 region
  bf16*  hbuf  = (bf16*)hreg;
  bf16*  xzAh  = (bf16*)hreg;
  bf16*  xzBh  = (bf16*)(hreg + 3145728);      // 2,359,296 bf16 = 1,179,648 f32
  float* xdblB = hreg + 3145728 + 1179648;     // 2,949,120 (rows of BROW=20 f32)
  float* xdblC = xdblB + 2949120;              // 2,359,296 (rows of 16 f32)
  float* ssum  = xdblC + 2359296;              // 196,608 used (region 393,216)
  bf16*  ydir  = (bf16*)(ssum + 393216);       // 9,437,184 bf16 = 4,718,592 f32
  float* xmR   = ssum + 393216 + 4718592;      // 1,179,648 (xch early, xm later)
  bf16*  xch   = (bf16*)xmR;
  float* xm    = xmR;
  float* st    = xmR + 1179648;                // 512
  float* inm = st, *inr = st + 128, *xmean = st + 256, *xmaxv = st + 384;
  float* aux   = st + 512;                     // 4,608
  bf16*  wh    = (bf16*)(aux + 4608);          // 9,216 bf16 = 4,608 f32 region
  float* cumS  = aux + 4608 + 4608;            // 196,608 used (region 393,216)
  float* segH  = cumS + 393216;                // 524,288 (32 segments)
  float* segS  = segH + 524288;                // 32,768
  bf16*  xcht  = (bf16*)(segS + 32768);        // 2,359,296 bf16 = 1,179,648 f32

  float* outp = (float*)d_out;
  float* down = outp;
  float* skipo = outp + DOWN_SZ;

  dim3 b256(256);
  int nEl = B_ * C_ * L_;

  k_front<<<dim3(L_ / 32, BB_), b256, 0, stream>>>(x, dw33w, dw33b, lnw, lnb, inw,
                                                   xpw, alog, xd, xzAh, xzBh, wh, aux);
  k_dwsilu<<<dim3(L_ / 2 * 32 / 256, BB_), b256, 0, stream>>>(xzAh, cw, cb, xch, xcht);
  k_xdbl_mfma<<<dim3(L_ / 64, BB_, 3), b256, 0, stream>>>(xch, wh, xdblB, xdblC);
  k_scan1<<<dim3(CH_ / 4, K_, BB_), b256, 0, stream>>>(xdblB, xch, xcht, dtw, dtb, aux, hbuf, ssum);
  k_scan2a<<<dim3(BB_ * K_ * SEGN * DI_ * N_ / 256), b256, 0, stream>>>(aux, ssum, hbuf, cumS, segH, segS);
  k_scan2b<<<dim3(BB_ * K_ * DI_ * N_ / 256), b256, 0, stream>>>(aux, segH, segS);
  k_scan3<<<dim3(CH_ / 4, K_, BB_), b256, 0, stream>>>(xdblB, xdblC, xch, xcht, dtw, dtb, Dsw,
                                                      aux, hbuf, cumS, segH, ydir);
  k_combine<<<dim3(L_ / 8, BB_), b256, 0, stream>>>(ydir, xzBh, xd, onw, onb, outw, mssc, xm);
  k_stats<<<dim3(B_ * C_), dim3(1024), 0, stream>>>(xm, x, inm, inr, xmean, xmaxv);
  k_axbn<<<dim3(nEl / 512), b256, 0, stream>>>(xm, x, inm, inr, msw, msb, xmean, xmaxv,
                                              maw, mab, ahw, ahb, aww, awb,
                                              bnw, bnb, bnm, bnv, skipo);
  k_pwpool<<<dim3(48, B_, 4), b256, 0, stream>>>(skipo, pww, pwb, down);
}

// Round 17
// 276.018 us; speedup vs baseline: 1.0464x; 1.0464x over previous
//
#include <hip/hip_runtime.h>
#include <hip/hip_bf16.h>

typedef __hip_bfloat16 bf16;
#define DEV __device__ __forceinline__

constexpr int B_ = 2, C_ = 64, H_ = 96, W_ = 96, L_ = 9216;
constexpr int HD_ = 32, DI_ = 64, N_ = 16, K_ = 4, BB_ = 4;
constexpr int OC_ = 128;
constexpr int CH_ = 384, CL_ = 24;          // scan chunking: 384 chunks of 24 steps
constexpr int SEGN = 32, SEGC = 12;         // scan2: 32 segments x 12 chunks
constexpr int BROW = 20;                    // f32 slots per scan-order B row (16 B + t0,t1 + pad2)
constexpr float EPSF = 1e-5f;
constexpr int DOWN_SZ = B_ * OC_ * 48 * 48; // 589824

typedef __attribute__((ext_vector_type(8))) short short8;   // 8 bf16 (4 VGPRs)
typedef __attribute__((ext_vector_type(4))) float f32x4;    // MFMA accumulator / b128 LDS read
typedef __attribute__((ext_vector_type(2))) float f32x2;    // packed v_pk_* pair

DEV float softplusf(float x) { return x > 15.f ? x : __logf(1.f + __expf(x)); }
DEV float b2f(bf16 v) { return __bfloat162float(v); }
DEV float lo16f(unsigned v) { return __uint_as_float(v << 16); }
DEV float hi16f(unsigned v) { return __uint_as_float(v & 0xffff0000u); }
DEV f32x2 pk2(unsigned w) { f32x2 r = {lo16f(w), hi16f(w)}; return r; }
DEV f32x2 lo2(f32x4 q) { f32x2 r = {q.x, q.y}; return r; }
DEV f32x2 hi2(f32x4 q) { f32x2 r = {q.z, q.w}; return r; }
DEV unsigned pkbf(float a, float b) {
  __hip_bfloat162 t;
  t.x = __float2bfloat16(a);
  t.y = __float2bfloat16(b);
  return *reinterpret_cast<unsigned*>(&t);
}
DEV void unpk8(uint4 a, float* v) {
  v[0] = lo16f(a.x); v[1] = hi16f(a.x); v[2] = lo16f(a.y); v[3] = hi16f(a.y);
  v[4] = lo16f(a.z); v[5] = hi16f(a.z); v[6] = lo16f(a.w); v[7] = hi16f(a.w);
}
DEV void unpk(uint4 a, uint4 b, float* v) {
  unpk8(a, v); unpk8(b, v + 8);
}

// log(1..16): detect A[n] = (n+1)*A[0] structure (VMamba default A_logs)
__constant__ float kLogN[16] = {
  0.0f, 0.69314718f, 1.09861229f, 1.38629436f, 1.60943791f, 1.79175947f,
  1.94591015f, 2.07944154f, 2.19722458f, 2.30258509f, 2.39789527f,
  2.48490665f, 2.56494936f, 2.63905733f, 2.70805020f, 2.77258872f};

// 16 decay powers e1^(n+1) as 8 packed pairs: {e1,e2},{e3,e4},...,{e15,e16}
DEV void pow_tree2(float e1, f32x2* ep) {
  float e2 = e1 * e1;
  ep[0].x = e1; ep[0].y = e2;
  f32x2 b2v = {e2, e2};
  ep[1] = ep[0] * b2v;                       // e3,e4
  float e4 = ep[1].y;
  f32x2 b4v = {e4, e4};
  ep[2] = ep[0] * b4v;                       // e5,e6
  ep[3] = ep[1] * b4v;                       // e7,e8
  float e8 = ep[3].y;
  f32x2 b8v = {e8, e8};
  ep[4] = ep[0] * b8v;                       // e9,e10
  ep[5] = ep[1] * b8v;                       // e11,e12
  ep[6] = ep[2] * b8v;                       // e13,e14
  ep[7] = ep[3] * b8v;                       // e15,e16
}

// ---------------- 1: FRONT — wprep + depthwise3x3 + LN(32) + in_proj (32-idx tiles) ----------------
__global__ __launch_bounds__(256, 4) void k_front(
    const float* __restrict__ x, const float* __restrict__ dw33w,
    const float* __restrict__ dw33b, const float* __restrict__ lnw,
    const float* __restrict__ lnb, const float* __restrict__ inw,
    const float* __restrict__ xpw, const float* __restrict__ alog,
    float* __restrict__ xd, bf16* __restrict__ xzAh, bf16* __restrict__ xzBh,
    bf16* __restrict__ wh, float* __restrict__ aux) {
  int bb = blockIdx.y, t = threadIdx.x;
  int b = bb & 1, co = (bb >> 1) * HD_;
  int idx0 = blockIdx.x * 32;
  if (bb == 0) {
    int i = blockIdx.x * 256 + t;
    if (i < 144 * 64) {
      int n = i >> 6;
      wh[i] = __float2bfloat16(n < 136 ? xpw[i] : 0.f);
    }
    if (blockIdx.x == 0) {
      int kd = t;  // 256 = K*DI
      const float* al = alog + kd * N_;
      float a0 = al[0];
      bool lin = true;
#pragma unroll
      for (int n = 1; n < N_; n++) lin = lin && (fabsf(al[n] - a0 - kLogN[n]) < 3e-5f);
      aux[kd] = -__expf(a0);
      aux[256 + kd] = lin ? 1.f : 0.f;
#pragma unroll
      for (int n = 0; n < N_; n++) aux[512 + kd * N_ + n] = -__expf(al[n]);
    }
  }
  __shared__ float xds[32 * 36];
  __shared__ float meanA[32], rstdA[32];
  for (int i = t; i < 1024; i += 256) {
    int cl = i >> 5, ii = i & 31;
    int sp = idx0 + ii, wi = sp % 96, hi = sp / 96;
    int cg = b * C_ + co + cl;
    float acc = dw33b[co + cl];
#pragma unroll
    for (int dy = -1; dy <= 1; dy++) {
      int hh = hi + dy; if (hh < 0 || hh >= H_) continue;
#pragma unroll
      for (int dx = -1; dx <= 1; dx++) {
        int ww = wi + dx; if (ww < 0 || ww >= W_) continue;
        acc = fmaf(x[(size_t)cg * L_ + sp + dy * 96 + dx],
                   dw33w[(co + cl) * 9 + (dy + 1) * 3 + (dx + 1)], acc);
      }
    }
    xds[cl * 36 + ii] = acc;
    xd[(size_t)cg * L_ + sp] = acc;
  }
  __syncthreads();
  if (t < 32) {
    float s = 0.f, sq = 0.f;
#pragma unroll
    for (int c = 0; c < 32; c++) { float v = xds[c * 36 + t]; s += v; sq = fmaf(v, v, sq); }
    float mean = s * (1.f / HD_);
    float var = sq * (1.f / HD_) - mean * mean;
    meanA[t] = mean; rstdA[t] = rsqrtf(var + EPSF);
  }
  __syncthreads();
  for (int i = t; i < 1024; i += 256) {
    int c = i >> 5, idx = i & 31;
    float v = xds[c * 36 + idx];
    xds[c * 36 + idx] = (v - meanA[idx]) * rstdA[idx] * lnw[c] + lnb[c];
  }
  __syncthreads();
  int oc = t & 127, g = t >> 7;
  float acc[16];
#pragma unroll
  for (int j = 0; j < 16; j++) acc[j] = 0.f;
  for (int c = 0; c < 32; c++) {
    float wv = inw[c * 128 + oc];
    const float4* row = reinterpret_cast<const float4*>(&xds[c * 36 + g * 16]);
#pragma unroll
    for (int j4 = 0; j4 < 4; j4++) {
      float4 xv = row[j4];
      acc[j4 * 4 + 0] = fmaf(xv.x, wv, acc[j4 * 4 + 0]);
      acc[j4 * 4 + 1] = fmaf(xv.y, wv, acc[j4 * 4 + 1]);
      acc[j4 * 4 + 2] = fmaf(xv.z, wv, acc[j4 * 4 + 2]);
      acc[j4 * 4 + 3] = fmaf(xv.w, wv, acc[j4 * 4 + 3]);
    }
  }
  int occ = oc & 63;
  if (oc < 64) {
#pragma unroll
    for (int j = 0; j < 16; j++)
      xzAh[(size_t)(bb * L_ + idx0 + g * 16 + j) * 64 + occ] = __float2bfloat16(acc[j]);
  } else {
#pragma unroll
    for (int j = 0; j < 16; j++)
      xzBh[(size_t)(bb * L_ + idx0 + g * 16 + j) * 64 + occ] = __float2bfloat16(acc[j]);
  }
}

// ---------------- 2: depthwise 3x3 + SiLU — 2 rows x 2 channels per thread ----------------
__global__ void k_dwsilu(const bf16* __restrict__ xzAh, const float* __restrict__ cw,
                         const float* __restrict__ cb, bf16* __restrict__ xch,
                         bf16* __restrict__ xcht) {
  int t = blockIdx.x * 256 + threadIdx.x;       // over (L/2)*32 pair-items
  int dp = t & 31, rp = t >> 5;                 // rp in [0, 4608)
  int bb = blockIdx.y;
  int d0 = dp * 2;
  int wi = rp % 96, hp = rp / 96;
  int hi0 = hp * 2;                             // rows hi0, hi0+1
  const unsigned* src = (const unsigned*)xzAh;  // bf16 pairs
  float a00 = cb[d0], a01 = cb[d0 + 1];
  float a10 = a00, a11 = a01;
#pragma unroll
  for (int r4 = 0; r4 < 4; r4++) {
    int rr = hi0 - 1 + r4;
    if (rr < 0 || rr >= H_) continue;
#pragma unroll
    for (int c3 = 0; c3 < 3; c3++) {
      int cc = wi - 1 + c3;
      if (cc < 0 || cc >= W_) continue;
      unsigned v = src[(size_t)(bb * L_ + rr * 96 + cc) * 32 + dp];
      float vl = lo16f(v), vh = hi16f(v);
      if (r4 <= 2) {                            // row0: dy = r4-1 -> weight row r4
        a00 = fmaf(vl, cw[d0 * 9 + r4 * 3 + c3], a00);
        a01 = fmaf(vh, cw[(d0 + 1) * 9 + r4 * 3 + c3], a01);
      }
      if (r4 >= 1) {                            // row1: dy = r4-2 -> weight row r4-1
        a10 = fmaf(vl, cw[d0 * 9 + (r4 - 1) * 3 + c3], a10);
        a11 = fmaf(vh, cw[(d0 + 1) * 9 + (r4 - 1) * 3 + c3], a11);
      }
    }
  }
  a00 = a00 / (1.f + __expf(-a00));
  a01 = a01 / (1.f + __expf(-a01));
  a10 = a10 / (1.f + __expf(-a10));
  a11 = a11 / (1.f + __expf(-a11));
  unsigned o0 = pkbf(a00, a01), o1 = pkbf(a10, a11);
  int idx0 = hi0 * 96 + wi;
  ((unsigned*)xch)[((size_t)bb * L_ + idx0) * 32 + dp] = o0;
  ((unsigned*)xch)[((size_t)bb * L_ + idx0 + 96) * 32 + dp] = o1;
  int it0 = wi * 96 + hi0;
  ((unsigned*)xcht)[((size_t)bb * L_ + it0) * 32 + dp] = o0;
  ((unsigned*)xcht)[((size_t)bb * L_ + it0 + 1) * 32 + dp] = o1;
}

// ---------------- 3: x_dbl proj via MFMA -> scan-order xdblB / xdblC (f32, nt split on z) ----------------
__global__ __launch_bounds__(256, 4) void k_xdbl_mfma(
    const bf16* __restrict__ xch, const bf16* __restrict__ wh,
    float* __restrict__ xdblB, float* __restrict__ xdblC) {
  int w = threadIdx.x >> 6, lane = threadIdx.x & 63;
  int bb = blockIdx.y;
  int mtile = blockIdx.x * 4 + w;
  int idx0 = mtile * 16;
  int m = lane & 15, quad = lane >> 4;
  const bf16* arow = xch + ((size_t)bb * L_ + idx0 + m) * 64 + quad * 8;
  short8 a0 = *reinterpret_cast<const short8*>(arow);
  short8 a1 = *reinterpret_cast<const short8*>(arow + 32);
  int ntb = blockIdx.z * 3;
#pragma unroll
  for (int it = 0; it < 3; it++) {
    int nt = ntb + it;
    int n = nt * 16 + m;
    const bf16* brow = wh + n * 64 + quad * 8;
    short8 b0 = *reinterpret_cast<const short8*>(brow);
    short8 b1 = *reinterpret_cast<const short8*>(brow + 32);
    f32x4 acc = {0.f, 0.f, 0.f, 0.f};
    acc = __builtin_amdgcn_mfma_f32_16x16x32_bf16(a0, b0, acc, 0, 0, 0);
    acc = __builtin_amdgcn_mfma_f32_16x16x32_bf16(a1, b1, acc, 0, 0, 0);
    if (n < 136) {
      int k4 = (n >= 102) ? 3 : (n >= 68) ? 2 : (n >= 34) ? 1 : 0;
      int c = n - k4 * 34;
#pragma unroll
      for (int i = 0; i < 4; i++) {
        int r = idx0 + quad * 4 + i;
        int hi2 = r / 96, wi2 = r - hi2 * 96;
        int tr = wi2 * 96 + hi2;
        int ls = (k4 == 0) ? r : (k4 == 1) ? tr : (k4 == 2) ? (L_ - 1 - r) : (L_ - 1 - tr);
        size_t row = (size_t)(bb * K_ + k4) * L_ + ls;
        if (c < 2)       xdblB[row * BROW + 16 + c] = acc[i];
        else if (c < 18) xdblB[row * BROW + (c - 2)] = acc[i];
        else             xdblC[row * 16 + (c - 18)] = acc[i];
      }
    }
  }
}

// ---------------- 4: scan1 — per-chunk summaries; LDS b128 broadcasts, reg-prefetched u ----------------
__global__ __launch_bounds__(256, 4) void k_scan1(
    const float* __restrict__ xdblB, const bf16* __restrict__ xch,
    const bf16* __restrict__ xcht, const float* __restrict__ dtw,
    const float* __restrict__ dtb, const float* __restrict__ aux,
    bf16* __restrict__ hbuf, float* __restrict__ ssum) {
  int w = threadIdx.x >> 6, d = threadIdx.x & 63;
  int bx = blockIdx.x;
  int chunk = bx * 4 + w, k = blockIdx.y, bb = blockIdx.z;
  const float* bB = xdblB + (size_t)(bb * K_ + k) * L_ * BROW;
  __shared__ __align__(16) float sB[96 * BROW];   // 7680 B
  {
    const uint4* src = (const uint4*)(bB + (size_t)bx * 96 * BROW);
    uint4* dst = (uint4*)sB;
    for (int i = threadIdx.x; i < 480; i += 256) dst[i] = src[i];
  }
  __syncthreads();
  float w0 = dtw[(k * DI_ + d) * 2 + 0], w1 = dtw[(k * DI_ + d) * 2 + 1];
  float bia = dtb[k * DI_ + d];
  float A1 = aux[k * 64 + d];
  bool chain = (__ballot(aux[256 + k * 64 + d] > 0.5f) == ~0ull);
  const bf16* ub = ((k & 1) ? xcht : xch) + (size_t)bb * L_ * DI_;
  int ls0 = chunk * CL_;
  int uidx0 = (k & 2) ? (L_ - 1 - ls0) : ls0;
  int ustep = (k & 2) ? -1 : 1;
  float S = 0.f;
  size_t base = (size_t)((bb * K_ + k) * CH_ + chunk) * DI_ + d;
  if (chain) {
    // prefetch all u for the chunk (independent loads, static indexing)
    float uv[CL_];
    const bf16* up = ub + (size_t)uidx0 * DI_ + d;
#pragma unroll
    for (int s = 0; s < CL_; s++) uv[s] = b2f(up[s * ustep * DI_]);
    f32x2 h2[8];
#pragma unroll
    for (int i = 0; i < 8; i++) { h2[i].x = 0.f; h2[i].y = 0.f; }
#pragma unroll
    for (int s = 0; s < CL_; s++) {
      const float* p = sB + (w * CL_ + s) * BROW;
      f32x4 q0 = *(const f32x4*)p;
      f32x4 q1 = *(const f32x4*)(p + 4);
      f32x4 q2 = *(const f32x4*)(p + 8);
      f32x4 q3 = *(const f32x4*)(p + 12);
      f32x2 tt = *(const f32x2*)(p + 16);
      float dt = softplusf(fmaf(tt.x, w0, fmaf(tt.y, w1, bia)));
      S += dt;
      float du = dt * uv[s];
      f32x2 du2 = {du, du};
      f32x2 ep2[8];
      pow_tree2(__expf(dt * A1), ep2);
      h2[0] = ep2[0] * h2[0] + du2 * lo2(q0);
      h2[1] = ep2[1] * h2[1] + du2 * hi2(q0);
      h2[2] = ep2[2] * h2[2] + du2 * lo2(q1);
      h2[3] = ep2[3] * h2[3] + du2 * hi2(q1);
      h2[4] = ep2[4] * h2[4] + du2 * lo2(q2);
      h2[5] = ep2[5] * h2[5] + du2 * hi2(q2);
      h2[6] = ep2[6] * h2[6] + du2 * lo2(q3);
      h2[7] = ep2[7] * h2[7] + du2 * hi2(q3);
    }
    uint4 o0, o1;
    o0.x = pkbf(h2[0].x, h2[0].y); o0.y = pkbf(h2[1].x, h2[1].y);
    o0.z = pkbf(h2[2].x, h2[2].y); o0.w = pkbf(h2[3].x, h2[3].y);
    o1.x = pkbf(h2[4].x, h2[4].y); o1.y = pkbf(h2[5].x, h2[5].y);
    o1.z = pkbf(h2[6].x, h2[6].y); o1.w = pkbf(h2[7].x, h2[7].y);
    *(uint4*)(hbuf + base * N_) = o0;
    *(uint4*)(hbuf + base * N_ + 8) = o1;
  } else {
    float h[N_];
#pragma unroll
    for (int n = 0; n < N_; n++) h[n] = 0.f;
    float A[N_];
#pragma unroll
    for (int n = 0; n < N_; n++) A[n] = aux[512 + (k * 64 + d) * N_ + n];
    for (int s = 0; s < CL_; s++) {
      const float* p = sB + (w * CL_ + s) * BROW;
      float u = b2f(ub[(size_t)(uidx0 + s * ustep) * DI_ + d]);
      float dt = softplusf(fmaf(p[16], w0, fmaf(p[17], w1, bia)));
      S += dt;
      float du = dt * u;
#pragma unroll
      for (int n = 0; n < N_; n++) h[n] = fmaf(__expf(dt * A[n]), h[n], du * p[n]);
    }
#pragma unroll
    for (int n = 0; n < N_; n++) hbuf[base * N_ + n] = __float2bfloat16(h[n]);
  }
  ssum[base] = S;
}

// ---------------- 5: scan2a — segment-local exclusive scan + raw segment totals ----------------
__global__ __launch_bounds__(256, 4) void k_scan2a(
    const float* __restrict__ aux, const float* __restrict__ ssum,
    bf16* __restrict__ hbuf, float* __restrict__ cumS,
    float* __restrict__ segH, float* __restrict__ segS) {
  int t = blockIdx.x * 256 + threadIdx.x;      // 524288
  int n = t & 15, d = (t >> 4) & 63, kk = (t >> 10) & 3, bb = (t >> 12) & 3, seg = t >> 14;
  float A = aux[512 + (kk * 64 + d) * N_ + n];
  size_t row = (size_t)(bb * K_ + kk) * CH_ * DI_ + d;
  float hp = 0.f, Sc = 0.f;
#pragma unroll 4
  for (int j = 0; j < SEGC; j++) {
    int c = seg * SEGC + j;
    size_t sb = row + (size_t)c * DI_;
    float S = ssum[sb];
    float hl = b2f(hbuf[sb * N_ + n]);
    hbuf[sb * N_ + n] = __float2bfloat16(hp);
    if (n == 0) cumS[sb] = Sc;
    hp = fmaf(__expf(A * S), hp, hl);
    Sc += S;
  }
  size_t sbase = (size_t)(bb * K_ + kk) * SEGN + seg;
  segH[(sbase * DI_ + d) * N_ + n] = hp;
  if (n == 0) segS[sbase * DI_ + d] = Sc;
}

// ---------------- 6: scan2b — serial scan over 32 segments (tiny) ----------------
__global__ void k_scan2b(const float* __restrict__ aux, float* __restrict__ segH,
                         const float* __restrict__ segS) {
  int t = blockIdx.x * 256 + threadIdx.x;  // 16384
  int n = t & 15, d = (t >> 4) & 63, kk = (t >> 10) & 3, bb = t >> 12;
  float A = aux[512 + (kk * 64 + d) * N_ + n];
  float hp = 0.f;
  for (int seg = 0; seg < SEGN; seg++) {
    size_t sbase = (size_t)(bb * K_ + kk) * SEGN + seg;
    size_t si = (sbase * DI_ + d) * N_ + n;
    float H = segH[si];
    float E = __expf(A * segS[sbase * DI_ + d]);
    segH[si] = hp;                          // overwrite with segment-initial state
    hp = fmaf(E, hp, H);
  }
}

// ---------------- 7: scan3 — replay with prefixed segH init; headers hoisted above staging ----------------
__global__ __launch_bounds__(256, 4) void k_scan3(
    const float* __restrict__ xdblB, const float* __restrict__ xdblC,
    const bf16* __restrict__ xch, const bf16* __restrict__ xcht,
    const float* __restrict__ dtw, const float* __restrict__ dtb,
    const float* __restrict__ Dsw, const float* __restrict__ aux,
    const bf16* __restrict__ hbuf, const float* __restrict__ cumS,
    const float* __restrict__ segH, bf16* __restrict__ ydir) {
  int w = threadIdx.x >> 6, d = threadIdx.x & 63;
  int bx = blockIdx.x;
  int chunk = bx * 4 + w, k = blockIdx.y, bb = blockIdx.z;
  // --- early header loads: issue before LDS staging so latency overlaps it ---
  size_t base = (size_t)((bb * K_ + k) * CH_ + chunk) * DI_ + d;
  int seg = chunk / SEGC;
  size_t sbase = (size_t)(bb * K_ + k) * SEGN + seg;
  float Sc = cumS[base];
  const bf16* hb = hbuf + base * N_;
  uint4 qh0 = *(const uint4*)hb, qh1 = *(const uint4*)(hb + 8);
  const float* Hinp = segH + (sbase * DI_ + d) * N_;
  f32x4 hin0 = *(const f32x4*)Hinp;
  f32x4 hin1 = *(const f32x4*)(Hinp + 4);
  f32x4 hin2 = *(const f32x4*)(Hinp + 8);
  f32x4 hin3 = *(const f32x4*)(Hinp + 12);
  float w0 = dtw[(k * DI_ + d) * 2 + 0], w1 = dtw[(k * DI_ + d) * 2 + 1];
  float bia = dtb[k * DI_ + d];
  float Dk = Dsw[k * DI_ + d];
  float A1 = aux[k * 64 + d];
  bool chain = (__ballot(aux[256 + k * 64 + d] > 0.5f) == ~0ull);
  // --- LDS staging ---
  const float* bB = xdblB + (size_t)(bb * K_ + k) * L_ * BROW;
  const float* bC = xdblC + (size_t)(bb * K_ + k) * L_ * 16;
  __shared__ __align__(16) float sB[96 * BROW];   // 7680 B
  __shared__ __align__(16) float sC[96 * 16];     // 6144 B
  {
    const uint4* srcB = (const uint4*)(bB + (size_t)bx * 96 * BROW);
    uint4* dstB = (uint4*)sB;
    for (int i = threadIdx.x; i < 480; i += 256) dstB[i] = srcB[i];
    const uint4* srcC = (const uint4*)(bC + (size_t)bx * 96 * 16);
    uint4* dstC = (uint4*)sC;
    for (int i = threadIdx.x; i < 384; i += 256) dstC[i] = srcC[i];
  }
  __syncthreads();
  const bf16* ub = ((k & 1) ? xcht : xch) + (size_t)bb * L_ * DI_;
  bf16* yb = ydir + (size_t)(bb * K_ + k) * L_ * DI_;
  int ls0 = chunk * CL_;
  int uidx0 = (k & 2) ? (L_ - 1 - ls0) : ls0;
  int ustep = (k & 2) ? -1 : 1;
  if (chain) {
    float uv[CL_];
    const bf16* up = ub + (size_t)uidx0 * DI_ + d;
#pragma unroll
    for (int s = 0; s < CL_; s++) uv[s] = b2f(up[s * ustep * DI_]);
    f32x2 h2[8];
    {
      h2[0] = pk2(qh0.x); h2[1] = pk2(qh0.y); h2[2] = pk2(qh0.z); h2[3] = pk2(qh0.w);
      h2[4] = pk2(qh1.x); h2[5] = pk2(qh1.y); h2[6] = pk2(qh1.z); h2[7] = pk2(qh1.w);
      f32x2 ep2[8];
      pow_tree2(__expf(A1 * Sc), ep2);
      h2[0] = ep2[0] * lo2(hin0) + h2[0];
      h2[1] = ep2[1] * hi2(hin0) + h2[1];
      h2[2] = ep2[2] * lo2(hin1) + h2[2];
      h2[3] = ep2[3] * hi2(hin1) + h2[3];
      h2[4] = ep2[4] * lo2(hin2) + h2[4];
      h2[5] = ep2[5] * hi2(hin2) + h2[5];
      h2[6] = ep2[6] * lo2(hin3) + h2[6];
      h2[7] = ep2[7] * hi2(hin3) + h2[7];
    }
#pragma unroll
    for (int s = 0; s < CL_; s++) {
      int lr = w * CL_ + s;
      const float* p = sB + lr * BROW;
      const float* pc = sC + lr * 16;
      f32x4 q0 = *(const f32x4*)p;
      f32x4 q1 = *(const f32x4*)(p + 4);
      f32x4 q2 = *(const f32x4*)(p + 8);
      f32x4 q3 = *(const f32x4*)(p + 12);
      f32x2 tt = *(const f32x2*)(p + 16);
      f32x4 c0 = *(const f32x4*)pc;
      f32x4 c1 = *(const f32x4*)(pc + 4);
      f32x4 c2 = *(const f32x4*)(pc + 8);
      f32x4 c3 = *(const f32x4*)(pc + 12);
      float dt = softplusf(fmaf(tt.x, w0, fmaf(tt.y, w1, bia)));
      float du = dt * uv[s];
      f32x2 du2 = {du, du};
      f32x2 ep2[8];
      pow_tree2(__expf(dt * A1), ep2);
      f32x2 y2 = {0.f, 0.f};
      h2[0] = ep2[0] * h2[0] + du2 * lo2(q0);  y2 = h2[0] * lo2(c0) + y2;
      h2[1] = ep2[1] * h2[1] + du2 * hi2(q0);  y2 = h2[1] * hi2(c0) + y2;
      h2[2] = ep2[2] * h2[2] + du2 * lo2(q1);  y2 = h2[2] * lo2(c1) + y2;
      h2[3] = ep2[3] * h2[3] + du2 * hi2(q1);  y2 = h2[3] * hi2(c1) + y2;
      h2[4] = ep2[4] * h2[4] + du2 * lo2(q2);  y2 = h2[4] * lo2(c2) + y2;
      h2[5] = ep2[5] * h2[5] + du2 * hi2(q2);  y2 = h2[5] * hi2(c2) + y2;
      h2[6] = ep2[6] * h2[6] + du2 * lo2(q3);  y2 = h2[6] * lo2(c3) + y2;
      h2[7] = ep2[7] * h2[7] + du2 * hi2(q3);  y2 = h2[7] * hi2(c3) + y2;
      float y = fmaf(Dk, uv[s], y2.x + y2.y);
      yb[(size_t)(ls0 + s) * DI_ + d] = __float2bfloat16(y);
    }
  } else {
    float h[N_];
    float hin[N_];
    {
      *(f32x4*)(hin + 0) = hin0; *(f32x4*)(hin + 4) = hin1;
      *(f32x4*)(hin + 8) = hin2; *(f32x4*)(hin + 12) = hin3;
      unpk(qh0, qh1, h);
#pragma unroll
      for (int n = 0; n < N_; n++) {
        float A = aux[512 + (k * 64 + d) * N_ + n];
        h[n] = fmaf(__expf(A * Sc), hin[n], h[n]);
      }
    }
    float A[N_];
#pragma unroll
    for (int n = 0; n < N_; n++) A[n] = aux[512 + (k * 64 + d) * N_ + n];
    for (int s = 0; s < CL_; s++) {
      int lr = w * CL_ + s;
      const float* p = sB + lr * BROW;
      const float* pc = sC + lr * 16;
      float u = b2f(ub[(size_t)(uidx0 + s * ustep) * DI_ + d]);
      float dt = softplusf(fmaf(p[16], w0, fmaf(p[17], w1, bia)));
      float du = dt * u;
      float y = 0.f;
#pragma unroll
      for (int n = 0; n < N_; n++) {
        h[n] = fmaf(__expf(dt * A[n]), h[n], du * p[n]);
        y = fmaf(h[n], pc[n], y);
      }
      y = fmaf(Dk, u, y);
      yb[(size_t)(ls0 + s) * DI_ + d] = __float2bfloat16(y);
    }
  }
}

// ---------------- 8: combine — 2 idx/warp ILP; 4 dirs, LN(64)*silu(z), out_proj, residual ----------------
__global__ void k_combine(const bf16* __restrict__ ydir, const bf16* __restrict__ xzBh,
                          const float* __restrict__ xd, const float* __restrict__ onw,
                          const float* __restrict__ onb, const float* __restrict__ outw,
                          const float* __restrict__ mssc, float* __restrict__ xm) {
  int w = threadIdx.x >> 6, d = threadIdx.x & 63;
  int idxA = blockIdx.x * 8 + w * 2, bb = blockIdx.y;
  int idxB = idxA + 1;
  int b = bb & 1, co = (bb >> 1) * HD_;
  const bf16* yd = ydir + (size_t)bb * K_ * L_ * DI_;
  int hiA = idxA / 96, wiA = idxA - hiA * 96, ltA = wiA * 96 + hiA;
  int hiB = idxB / 96, wiB = idxB - hiB * 96, ltB = wiB * 96 + hiB;
  float yA = b2f(yd[((size_t)0 * L_ + idxA) * DI_ + d])
           + b2f(yd[((size_t)1 * L_ + ltA) * DI_ + d])
           + b2f(yd[((size_t)2 * L_ + (L_ - 1 - idxA)) * DI_ + d])
           + b2f(yd[((size_t)3 * L_ + (L_ - 1 - ltA)) * DI_ + d]);
  float yB = b2f(yd[((size_t)0 * L_ + idxB) * DI_ + d])
           + b2f(yd[((size_t)1 * L_ + ltB) * DI_ + d])
           + b2f(yd[((size_t)2 * L_ + (L_ - 1 - idxB)) * DI_ + d])
           + b2f(yd[((size_t)3 * L_ + (L_ - 1 - ltB)) * DI_ + d]);
  float sA = yA, qA = yA * yA, sB = yB, qB = yB * yB;
#pragma unroll
  for (int m = 1; m < 64; m <<= 1) {
    sA += __shfl_xor(sA, m, 64); qA += __shfl_xor(qA, m, 64);
    sB += __shfl_xor(sB, m, 64); qB += __shfl_xor(qB, m, 64);
  }
  float meanA = sA * (1.f / DI_);
  float rstdA = rsqrtf(qA * (1.f / DI_) - meanA * meanA + EPSF);
  float meanB = sB * (1.f / DI_);
  float rstdB = rsqrtf(qB * (1.f / DI_) - meanB * meanB + EPSF);
  float onwd = onw[d], onbd = onb[d];
  float ynA = (yA - meanA) * rstdA * onwd + onbd;
  float ynB = (yB - meanB) * rstdB * onwd + onbd;
  float zA = b2f(xzBh[(size_t)(bb * L_ + idxA) * 64 + d]);
  float zB = b2f(xzBh[(size_t)(bb * L_ + idxB) * 64 + d]);
  float gA = ynA * (zA / (1.f + __expf(-zA)));
  float gB = ynB * (zB / (1.f + __expf(-zB)));
  __shared__ __align__(16) float gs[8][DI_];
  gs[w * 2][d] = gA;
  gs[w * 2 + 1][d] = gB;
  __syncthreads();
  // split-dd out_proj: lanes d<32 sum dd=0..31, lanes d>=32 sum dd=32..63; shfl combines.
  int dh = d & 31;
  int ddb = (d >= 32) ? 32 : 0;
  const float* ga = &gs[w * 2][ddb];
  const float* gb = &gs[w * 2 + 1][ddb];
  float accA = 0.f, accB = 0.f;
#pragma unroll
  for (int j = 0; j < 8; j++) {
    float4 va = *(const float4*)(ga + j * 4);
    float4 vb = *(const float4*)(gb + j * 4);
    int dd = ddb + j * 4;
    float w0 = outw[(dd + 0) * HD_ + dh];
    float w1 = outw[(dd + 1) * HD_ + dh];
    float w2 = outw[(dd + 2) * HD_ + dh];
    float w3 = outw[(dd + 3) * HD_ + dh];
    accA = fmaf(va.x, w0, accA); accB = fmaf(vb.x, w0, accB);
    accA = fmaf(va.y, w1, accA); accB = fmaf(vb.y, w1, accB);
    accA = fmaf(va.z, w2, accA); accB = fmaf(vb.z, w2, accB);
    accA = fmaf(va.w, w3, accA); accB = fmaf(vb.w, w3, accB);
  }
  accA += __shfl_xor(accA, 32, 64);
  accB += __shfl_xor(accB, 32, 64);
  if (d < HD_) {
    float sc = mssc[0] + 1.f;
    size_t xiA = (size_t)(b * C_ + co + d) * L_ + idxA;
    size_t xiB = (size_t)(b * C_ + co + d) * L_ + idxB;
    xm[xiA] = sc * xd[xiA] + accA;
    xm[xiB] = sc * xd[xiB] + accB;
  }
}

// ---------------- 9: fused instance-norm stats (xm) + global mean/max pool (x), float4 ----------------
__global__ __launch_bounds__(1024) void k_stats(
    const float* __restrict__ xm, const float* __restrict__ x,
    float* __restrict__ inm, float* __restrict__ inr,
    float* __restrict__ xmean, float* __restrict__ xmax) {
  int bc = blockIdx.x, t = threadIdx.x;
  const float4* pm4 = (const float4*)(xm + (size_t)bc * L_);
  const float4* px4 = (const float4*)(x + (size_t)bc * L_);
  float s = 0.f, sq = 0.f, xs = 0.f, mx = -1e30f;
  for (int i = t; i < L_ / 4; i += 1024) {
    float4 v = pm4[i];
    s += (v.x + v.y) + (v.z + v.w);
    sq = fmaf(v.x, v.x, sq); sq = fmaf(v.y, v.y, sq);
    sq = fmaf(v.z, v.z, sq); sq = fmaf(v.w, v.w, sq);
    float4 xv = px4[i];
    xs += (xv.x + xv.y) + (xv.z + xv.w);
    mx = fmaxf(mx, fmaxf(fmaxf(xv.x, xv.y), fmaxf(xv.z, xv.w)));
  }
  __shared__ float red[64];
#pragma unroll
  for (int m = 1; m < 64; m <<= 1) {
    s += __shfl_xor(s, m, 64); sq += __shfl_xor(sq, m, 64);
    xs += __shfl_xor(xs, m, 64); mx = fmaxf(mx, __shfl_xor(mx, m, 64));
  }
  int wid = t >> 6;
  if ((t & 63) == 0) { red[wid] = s; red[16 + wid] = sq; red[32 + wid] = xs; red[48 + wid] = mx; }
  __syncthreads();
  if (t == 0) {
    s = 0.f; sq = 0.f; xs = 0.f; mx = -1e30f;
#pragma unroll
    for (int i = 0; i < 16; i++) {
      s += red[i]; sq += red[16 + i]; xs += red[32 + i]; mx = fmaxf(mx, red[48 + i]);
    }
    float mean = s * (1.f / L_);
    float var = sq * (1.f / L_) - mean * mean;
    inm[bc] = mean;
    inr[bc] = rsqrtf(var + EPSF);
    xmean[bc] = xs * (1.f / L_);
    xmax[bc] = mx;
  }
}

// ---------------- 10: axbn — 512 elems/block, 2/thread; IN+leaky+gate + axial convs + BN + relu ----------------
__global__ void k_axbn(const float* __restrict__ xm, const float* __restrict__ x,
                       const float* __restrict__ inm, const float* __restrict__ inr,
                       const float* __restrict__ msw, const float* __restrict__ msb,
                       const float* __restrict__ xmean, const float* __restrict__ xmax,
                       const float* __restrict__ maw, const float* __restrict__ mab,
                       const float* __restrict__ hw, const float* __restrict__ hb,
                       const float* __restrict__ wwt, const float* __restrict__ wb,
                       const float* __restrict__ bnw, const float* __restrict__ bnb,
                       const float* __restrict__ bnm, const float* __restrict__ bnv,
                       float* __restrict__ skipo) {
  constexpr int NEL = B_ * C_ * L_;
  int t0 = blockIdx.x * 512;
  int bc = t0 / L_, c = bc & 63, b = bc >> 6;   // uniform per block (512 | L)
  __shared__ float gsh;
  __shared__ float sxs[704];                    // [t0-96, t0+608) post-IN/leaky/gate values
  if (threadIdx.x < 64) {
    int ic = threadIdx.x;
    float p = xmean[b * 64 + ic] * maw[(c * 128 + ic) * 9 + 4]
            + xmax[b * 64 + ic] * maw[(c * 128 + 64 + ic) * 9 + 4];
#pragma unroll
    for (int m = 1; m < 64; m <<= 1) p += __shfl_xor(p, m, 64);
    if (ic == 0) gsh = 1.f / (1.f + __expf(-(p + mab[c])));
  }
  __syncthreads();
  float gate = gsh, im = inm[bc], ir = inr[bc], mw = msw[c], mb = msb[c];
  // stage: halo values outside valid row range are never consumed (guards below)
  for (int i = threadIdx.x; i < 704; i += 256) {
    int tt = t0 - 96 + i;
    tt = tt < 0 ? 0 : (tt >= NEL ? NEL - 1 : tt);
    float v = xm[tt];
    v = (v - im) * ir * mw + mb;
    v = v > 0.f ? v : 0.01f * v;
    sxs[i] = v + gate * x[tt];
  }
  __syncthreads();
  float hw0 = hw[c * 3], hw1 = hw[c * 3 + 1], hw2 = hw[c * 3 + 2];
  float ww0 = wwt[c * 3], ww1 = wwt[c * 3 + 1], ww2 = wwt[c * 3 + 2];
  float hbc = hb[c], wbc = wb[c];
  float bnr = rsqrtf(bnv[c] + EPSF) * bnw[c];
  float bnmc = bnm[c], bnbc = bnb[c];
#pragma unroll
  for (int e = 0; e < 2; e++) {
    int tid = e * 256 + threadIdx.x;
    int t = t0 + tid;
    int li = 96 + tid;
    int wi = t % W_, hi = (t / W_) % H_;
    float a = sxs[li];
    float hacc = hbc;
    if (hi > 0)      hacc = fmaf(sxs[li - 96], hw0, hacc);
    hacc = fmaf(a, hw1, hacc);
    if (hi < H_ - 1) hacc = fmaf(sxs[li + 96], hw2, hacc);
    float wacc = wbc;
    if (wi > 0)      wacc = fmaf(sxs[li - 1], ww0, wacc);
    wacc = fmaf(a, ww1, wacc);
    if (wi < W_ - 1) wacc = fmaf(sxs[li + 1], ww2, wacc);
    float v = a + hacc + wacc;
    float sv = (v - bnmc) * bnr + bnbc;
    skipo[t] = fmaxf(sv, 0.f);
  }
}

// ---------------- 11: 1x1 conv (64->128) + 2x2 maxpool -> down (oc split over z) ----------------
__global__ void k_pwpool(const float* __restrict__ skipo, const float* __restrict__ pww,
                         const float* __restrict__ pwb, float* __restrict__ down) {
  int h2 = blockIdx.x, b = blockIdx.y, t = threadIdx.x;
  int oc0 = blockIdx.z * 32;
  __shared__ __align__(8) float sk[64 * 192];  // [c][r(2)][w(96)]
  for (int i = t; i < 64 * 192; i += 256) {
    int c = i / 192, rw = i % 192, r = rw / 96, wcol = rw % 96;
    sk[i] = skipo[((size_t)(b * C_ + c) * H_ + (2 * h2 + r)) * W_ + wcol];
  }
  __syncthreads();
  for (int o = t; o < 32 * 48; o += 256) {
    int oc = oc0 + o / 48, w2 = o % 48;
    float s0 = 0.f, s1 = 0.f, s2 = 0.f, s3 = 0.f;
#pragma unroll 8
    for (int c = 0; c < 64; c++) {
      float wv = pww[oc * 64 + c];
      const float2* sp = (const float2*)&sk[c * 192 + 2 * w2];
      float2 r0 = sp[0];        // row 0: w, w+1
      float2 r1 = sp[48];       // row 1: w, w+1 (+96 floats)
      s0 = fmaf(r0.x, wv, s0);
      s1 = fmaf(r0.y, wv, s1);
      s2 = fmaf(r1.x, wv, s2);
      s3 = fmaf(r1.y, wv, s3);
    }
    float v = fmaxf(fmaxf(s0, s1), fmaxf(s2, s3)) + pwb[oc];
    down[((size_t)(b * OC_ + oc) * 48 + h2) * 48 + w2] = v;
  }
}

extern "C" void kernel_launch(void* const* d_in, const int* in_sizes, int n_in,
                              void* d_out, int out_size, void* d_ws, size_t ws_size,
                              hipStream_t stream) {
  const float* x     = (const float*)d_in[0];
  const float* dw33w = (const float*)d_in[1];
  const float* dw33b = (const float*)d_in[2];
  const float* msw   = (const float*)d_in[3];
  const float* msb   = (const float*)d_in[4];
  const float* mssc  = (const float*)d_in[5];
  const float* lnw   = (const float*)d_in[6];
  const float* lnb   = (const float*)d_in[7];
  const float* inw   = (const float*)d_in[8];
  const float* cw    = (const float*)d_in[9];
  const float* cb    = (const float*)d_in[10];
  const float* xpw   = (const float*)d_in[11];
  const float* dtw   = (const float*)d_in[12];
  const float* dtb   = (const float*)d_in[13];
  const float* alog  = (const float*)d_in[14];
  const float* Dsw   = (const float*)d_in[15];
  const float* onw   = (const float*)d_in[16];
  const float* onb   = (const float*)d_in[17];
  const float* outw  = (const float*)d_in[18];
  const float* maw   = (const float*)d_in[19];
  const float* mab   = (const float*)d_in[20];
  const float* ahw   = (const float*)d_in[21];
  const float* ahb   = (const float*)d_in[22];
  const float* aww   = (const float*)d_in[23];
  const float* awb   = (const float*)d_in[24];
  const float* pww   = (const float*)d_in[25];
  const float* pwb   = (const float*)d_in[26];
  const float* bnw   = (const float*)d_in[27];
  const float* bnb   = (const float*)d_in[28];
  const float* bnm   = (const float*)d_in[29];
  const float* bnv   = (const float*)d_in[30];

  // workspace layout (f32 units) — hbuf correctly sized:
  // hbuf = BB*K*CH*DI*N bf16 = 6,291,456 bf16 = 3,145,728 f32.
  float* ws = (float*)d_ws;
  float* xd    = ws;                           // 1,179,648
  float* hreg  = xd + 1179648;                 // 3,145,728 (hbuf; xzAh bf16 overlays head, dead pre-scan1)
  bf16*  hbuf  = (bf16*)hreg;
  bf16*  xzAh  = (bf16*)hreg;
  bf16*  xzBh  = (bf16*)(hreg + 3145728);      // 2,359,296 bf16 = 1,179,648 f32
  float* xdblB = hreg + 3145728 + 1179648;     // 2,949,120 (rows of BROW=20 f32)
  float* xdblC = xdblB + 2949120;              // 2,359,296 (rows of 16 f32)
  float* ssum  = xdblC + 2359296;              // 393,216
  bf16*  ydir  = (bf16*)(ssum + 393216);       // 9,437,184 bf16 = 4,718,592 f32
  float* xmR   = ssum + 393216 + 4718592;      // 1,179,648 (xch early, xm later)
  bf16*  xch   = (bf16*)xmR;
  float* xm    = xmR;
  float* st    = xmR + 1179648;                // 512
  float* inm = st, *inr = st + 128, *xmean = st + 256, *xmaxv = st + 384;
  float* aux   = st + 512;                     // 4,608
  bf16*  wh    = (bf16*)(aux + 4608);          // 9,216 bf16 = 4,608 f32 region
  float* cumS  = aux + 4608 + 4608;            // 393,216
  float* segH  = cumS + 393216;                // 524,288 (32 segments)
  float* segS  = segH + 524288;                // 32,768
  bf16*  xcht  = (bf16*)(segS + 32768);        // 2,359,296 bf16 = 1,179,648 f32

  float* outp = (float*)d_out;
  float* down = outp;
  float* skipo = outp + DOWN_SZ;

  dim3 b256(256);
  int nEl = B_ * C_ * L_;

  k_front<<<dim3(L_ / 32, BB_), b256, 0, stream>>>(x, dw33w, dw33b, lnw, lnb, inw,
                                                   xpw, alog, xd, xzAh, xzBh, wh, aux);
  k_dwsilu<<<dim3(L_ / 2 * 32 / 256, BB_), b256, 0, stream>>>(xzAh, cw, cb, xch, xcht);
  k_xdbl_mfma<<<dim3(L_ / 64, BB_, 3), b256, 0, stream>>>(xch, wh, xdblB, xdblC);
  k_scan1<<<dim3(CH_ / 4, K_, BB_), b256, 0, stream>>>(xdblB, xch, xcht, dtw, dtb, aux, hbuf, ssum);
  k_scan2a<<<dim3(BB_ * K_ * SEGN * DI_ * N_ / 256), b256, 0, stream>>>(aux, ssum, hbuf, cumS, segH, segS);
  k_scan2b<<<dim3(BB_ * K_ * DI_ * N_ / 256), b256, 0, stream>>>(aux, segH, segS);
  k_scan3<<<dim3(CH_ / 4, K_, BB_), b256, 0, stream>>>(xdblB, xdblC, xch, xcht, dtw, dtb, Dsw,
                                                      aux, hbuf, cumS, segH, ydir);
  k_combine<<<dim3(L_ / 8, BB_), b256, 0, stream>>>(ydir, xzBh, xd, onw, onb, outw, mssc, xm);
  k_stats<<<dim3(B_ * C_), dim3(1024), 0, stream>>>(xm, x, inm, inr, xmean, xmaxv);
  k_axbn<<<dim3(nEl / 512), b256, 0, stream>>>(xm, x, inm, inr, msw, msb, xmean, xmaxv,
                                              maw, mab, ahw, ahb, aww, awb,
                                              bnw, bnb, bnm, bnv, skipo);
  k_pwpool<<<dim3(48, B_, 4), b256, 0, stream>>>(skipo, pww, pwb, down);
}